// Round 11
// baseline (59.107 us; speedup 1.0000x reference)
//
#include <hip/hip_runtime.h>

#define NB1   123
#define NCSd  96
#define SW    538
#define TPB   256
#define BT    16
#define STPB  128
#define PBLK  16      // k_post blocks; slice = B/PBLK = 2048

// ws layout: [0..B) float s2 per element (|1000*S|^2). Written by k_fast, read by k_post.

// ---- main: 2 elements per wave, float4-only staging (state+action), no fences ----
__global__ __launch_bounds__(TPB) void k_fast(const float* __restrict__ action,
                                              const float* __restrict__ state,
                                              float* __restrict__ s2arr,
                                              float* __restrict__ out) {
    __shared__ __align__(16) float st[4][1088];      // 2 state rows per wave (1076 used)
    __shared__ __align__(16) float sa[4][192];       // 2 action rows per wave
    __shared__ float ev[4][256];                     // 2 bus histograms per wave

    const int tid = threadIdx.x;
    const int w = tid >> 6, l = tid & 63;
    const long g = (long)blockIdx.x * 4 + w;         // wave id = element pair

    // ---- issue ALL global loads as dwordx4 before any use ----
    const float4* G4 = (const float4*)(state + g * (2 * SW));    // 4304B: 16B aligned
    const float4* A4 = (const float4*)(action + g * (2 * NCSd)); // 768B: 16B aligned
    float4 v0 = G4[l];
    float4 v1 = G4[l + 64];
    float4 v2 = G4[l + 128];
    float4 v3 = G4[l + 192];
    float4 v4 = make_float4(0.f, 0.f, 0.f, 0.f);
    const bool t4 = l < 269 - 256;                   // 13 tail lanes
    if (t4) v4 = G4[l + 256];
    float4 av = make_float4(0.f, 0.f, 0.f, 0.f);
    const bool ta = l < 48;
    if (ta) av = A4[l];

    // zero ev while loads are in flight (LDS-only)
    ev[w][l] = 0.f; ev[w][l + 64] = 0.f;
    ev[w][l + 128] = 0.f; ev[w][l + 192] = 0.f;

    // ---- LDS stores (DS pipe is in-order per wave; compiler inserts counted waits) ----
    float4* st4 = (float4*)st[w];
    st4[l] = v0; st4[l + 64] = v1; st4[l + 128] = v2; st4[l + 192] = v3;
    if (t4) st4[l + 256] = v4;
    float4* sa4 = (float4*)sa[w];
    if (ta) sa4[l] = av;

    // ---- per-element phase: 32 lanes each ----
    const int e = l >> 5, li = l & 31;
    const long b = 2 * g + e;
    const float* srow = st[w] + e * SW;
    const float* actp = sa[w] + e * NCSd;
    float* evp = ev[w] + e * 128;
    const float pr = srow[3];

    float cost = 0.f, usat = 0.f;
    #pragma unroll
    for (int s = 0; s < 3; ++s) {
        int i = li + 32 * s;
        float cap = srow[250 + 3 * i];               // stride-3: conflict-free
        float tl  = srow[251 + 3 * i];
        int   bus = (int)srow[252 + 3 * i];
        float a   = actp[i];
        float conn = cap > 0.f ? 1.f : 0.f;
        float mch = fminf(22.0f,  conn * (70.0f - cap) * 4.0f);   // /DT, DT=0.25
        float mds = fmaxf(-22.0f, conn * (15.0f - cap) * 4.0f);
        float p = fmaxf(fminf(22.17f * a, mch), mds);             // MAX_CS = -MIN_CS
        cost = fmaf(pr * p, 0.25f, cost);
        float nc = ceilf((cap + p * 0.25f) * 100.0f) * 0.01f;
        if (tl == 1.0f) { float d = nc - 70.0f; usat = fmaf(-10.0f * d, d, usat); }
        atomicAdd(&evp[bus], p);
    }

    // s2 = |1000*S|^2 = sum_k (ap+ev)^2 + rp^2  (DS in-order: atomics precede reads)
    float s2 = 0.f;
    #pragma unroll
    for (int s = 0; s < 4; ++s) {
        int k = li + 32 * s;
        if (k < NB1) {
            float apv = srow[4 + k] + evp[k];
            float rpv = srow[127 + k];
            s2 = fmaf(apv, apv, fmaf(rpv, rpv, s2));
        }
    }
    #pragma unroll
    for (int off = 16; off; off >>= 1) {
        s2   += __shfl_xor(s2, off);
        cost += __shfl_xor(cost, off);
        usat += __shfl_xor(usat, off);
    }

    if (li == 0) {
        out[b] = cost + usat;                        // voltage term handled by k_post
        s2arr[b] = s2;
    }
}

// ---- post: block-redundant threshold, scan slice, exact-solve flagged (expected 0) ----
__global__ __launch_bounds__(TPB) void k_post(const float* __restrict__ action,
                                              const float* __restrict__ state,
                                              const float* __restrict__ Kre,
                                              const float* __restrict__ Kim,
                                              const float* __restrict__ Lre,
                                              const float* __restrict__ Lim,
                                              const float* __restrict__ s2arr,
                                              float* __restrict__ out,
                                              int B) {
    __shared__ float wred[8];
    __shared__ float thr_s;
    __shared__ unsigned nflag_s;
    __shared__ unsigned list_s[2048];
    __shared__ float evb[128], cre_s[128], cim_s[128], vls_s[128];

    const int tid = threadIdx.x;
    const int w = tid >> 6, l = tid & 63;

    // ---- phase 1: R2 = max_j ||K_j||^2 over ALL rows, block-redundant ----
    float rmax2 = 0.f;
    #pragma unroll 4
    for (int r = 0; r < 16; ++r) {
        int j = r * 8 + 2 * w;
        #pragma unroll
        for (int dj = 0; dj < 2; ++dj) {
            int jj = j + dj;
            if (jj < NB1) {
                const float* kr = Kre + jj * NB1;
                const float* ki = Kim + jj * NB1;
                float a = kr[l], bb = ki[l];
                float s = fmaf(a, a, bb * bb);
                if (l < NB1 - 64) {
                    float a2 = kr[l + 64], b2 = ki[l + 64];
                    s = fmaf(a2, a2, fmaf(b2, b2, s));
                }
                #pragma unroll
                for (int off = 32; off; off >>= 1) s += __shfl_xor(s, off);
                rmax2 = fmaxf(rmax2, s);
            }
        }
    }
    float dw2 = 0.f;
    if (w == 0) {
        float dr = Lre[l] - 1.f, di = Lim[l];
        dw2 = fmaf(dr, dr, di * di);
        if (l + 64 < NB1) {
            float dr2 = Lre[l + 64] - 1.f, di2 = Lim[l + 64];
            dw2 = fmaxf(dw2, fmaf(dr2, dr2, di2 * di2));
        }
        #pragma unroll
        for (int off = 32; off; off >>= 1) dw2 = fmaxf(dw2, __shfl_xor(dw2, off));
    }
    if (l == 0) { wred[w] = rmax2; if (w == 0) wred[4] = dw2; }
    if (tid == 0) nflag_s = 0u;
    __syncthreads();
    if (tid == 0) {
        float r2 = fmaxf(fmaxf(wred[0], wred[1]), fmaxf(wred[2], wred[3]));
        float R  = sqrtf(r2);
        float dW = sqrtf(wred[4]);
        // safe <=> x < t*(1-dW-t), t = 0.0495-dW (exact inversion of dW + x/m(x) < 0.0495)
        float t = 0.0495f - dW;
        float q2max = -1.0f;
        if (t > 0.f && t < 1.0f - dW) {
            float xm = (t * (1.0f - dW - t) - 1e-7f) / 1.001f;
            if (xm > 0.f && R > 0.f) {
                float sm = xm / R * 1000.0f;          // s-scale (S = s/1000)
                q2max = sm * sm;
            }
        }
        thr_s = q2max;
    }
    __syncthreads();

    // ---- phase 2: scan slice, collect flagged ----
    const int slice = B / PBLK;                       // 2048
    const int base = blockIdx.x * slice;
    const float thr = thr_s;
    for (int i = tid; i < slice; i += TPB) {
        float s2 = s2arr[base + i];
        if (!(s2 <= thr)) {                           // also catches thr<0
            unsigned idx = atomicAdd(&nflag_s, 1u);
            list_s[idx] = (unsigned)(base + i);
        }
    }
    __syncthreads();
    const unsigned nflag = nflag_s;

    // ---- phase 3: exact fp32 solve per flagged element (expected: never) ----
    const int j = tid;
    const bool jok = (tid < 128) && (j < NB1);
    for (unsigned f = 0; f < nflag; ++f) {
        long b = (long)list_s[f];
        const float* srow = state + b * SW;
        if (tid < 128) evb[tid] = 0.f;
        __syncthreads();
        if (tid < NCSd) {
            float cap = srow[250 + 3 * tid];
            int   bus = (int)srow[252 + 3 * tid];
            float a   = action[b * NCSd + tid];
            float conn = cap > 0.f ? 1.f : 0.f;
            float mch = fminf(22.0f,  conn * (70.0f - cap) * 4.0f);
            float mds = fmaxf(-22.0f, conn * (15.0f - cap) * 4.0f);
            float p = fmaxf(fminf(22.17f * a, mch), mds);
            atomicAdd(&evb[bus], p);
        }
        __syncthreads();
        float Sre = jok ? (srow[4 + j] + evb[j]) * 0.001f : 0.f;
        float Sim = jok ? srow[127 + j] * 0.001f : 0.f;
        float Wre = jok ? Lre[j] : 1.f;
        float Wim = jok ? Lim[j] : 0.f;
        float vr = 1.f, vi = 0.f;
        for (int it = 0; it < 32; ++it) {             // fp32 fixpoint well before 32
            float d = vr * vr + vi * vi;
            float inv = 1.0f / d;
            if (tid < 128) {
                cre_s[tid] = jok ? (Sre * vr + Sim * vi) * inv : 0.f;
                cim_s[tid] = jok ? (Sre * vi - Sim * vr) * inv : 0.f;
            }
            __syncthreads();
            float ar = Wre, ai = Wim;
            if (jok) {
                for (int k = 0; k < NB1; ++k) {
                    float kr = Kre[j * NB1 + k], ki = Kim[j * NB1 + k];
                    ar = fmaf(kr, cre_s[k], fmaf(-ki, cim_s[k], ar));
                    ai = fmaf(kr, cim_s[k], fmaf( ki, cre_s[k], ai));
                }
            }
            vr = ar; vi = ai;
            __syncthreads();
        }
        if (tid < 128) {
            float vm = sqrtf(vr * vr + vi * vi);
            vls_s[tid] = jok ? fminf(0.f, 0.05f - fabsf(1.0f - vm)) : 0.f;
        }
        __syncthreads();
        if (tid == 0) {
            float s = 0.f;
            for (int k = 0; k < NB1; ++k) s += vls_s[k];
            out[b] += 1000.0f * s;
        }
        __syncthreads();
    }
}

// ================= legacy full-solve path (used only if ws too small) =================
__global__ __launch_bounds__(STPB) void k_main(
    const float* __restrict__ action, const float* __restrict__ state,
    const float* __restrict__ Kre, const float* __restrict__ Kim,
    const float* __restrict__ Lre, const float* __restrict__ Lim,
    float* __restrict__ out)
{
    __shared__ float ev[BT][STPB];
    __shared__ float costs_s[BT];
    __shared__ float usat_s[BT];
    __shared__ __align__(16) float2 cmat[STPB][BT + 2];
    __shared__ float vls[STPB][BT + 1];
    __shared__ float red[2];
    const int tid = threadIdx.x;
    const int e0  = blockIdx.x * BT;
    for (int x = tid; x < BT * STPB; x += STPB) ((float*)ev)[x] = 0.f;
    if (tid < BT) { costs_s[tid] = 0.f; usat_s[tid] = 0.f; }
    __syncthreads();
    for (int task = tid; task < BT * NCSd; task += STPB) {
        int e = task / NCSd, i = task - e * NCSd;
        long b = (long)(e0 + e);
        const float* srow = state + b * SW;
        float cap = srow[250 + 3 * i], tleft = srow[251 + 3 * i];
        int bus = (int)srow[252 + 3 * i];
        float a = action[b * NCSd + i];
        float conn = cap > 0.f ? 1.f : 0.f;
        float mch = fminf(22.0f, conn * (70.0f - cap) * 4.0f);
        float mds = fmaxf(-22.0f, conn * (15.0f - cap) * 4.0f);
        float power = fmaxf(fminf(22.17f * a, mch), mds);
        atomicAdd(&costs_s[e], srow[3] * power * 0.25f);
        float nc = ceilf((cap + power * 0.25f) * 100.0f) * 0.01f;
        if (tleft == 1.0f) { float d = nc - 70.0f; atomicAdd(&usat_s[e], -10.0f * d * d); }
        atomicAdd(&ev[e][bus], power);
    }
    __syncthreads();
    const int j = tid;
    const bool jok = j < NB1;
    float Wre = jok ? Lre[j] : 1.0f, Wim = jok ? Lim[j] : 0.0f;
    float Sre[BT], Sim[BT], vr[BT], vi[BT];
    #pragma unroll
    for (int e = 0; e < BT; ++e) {
        long b = (long)(e0 + e);
        float ap = jok ? state[b * SW + 4 + j] : 0.f;
        float rp = jok ? state[b * SW + 127 + j] : 0.f;
        Sre[e] = (ap + ev[e][j]) * 0.001f; Sim[e] = rp * 0.001f;
        vr[e] = 1.f; vi[e] = 0.f;
    }
    for (int it = 0; it < 100; ++it) {
        #pragma unroll
        for (int e = 0; e < BT; ++e) {
            float d = vr[e]*vr[e] + vi[e]*vi[e];
            float inv = 1.0f / d;
            cmat[j][e] = make_float2((Sre[e]*vr[e] + Sim[e]*vi[e]) * inv,
                                     (Sre[e]*vi[e] - Sim[e]*vr[e]) * inv);
        }
        __syncthreads();
        float ar[BT], ai[BT];
        #pragma unroll
        for (int e = 0; e < BT; ++e) { ar[e] = Wre; ai[e] = Wim; }
        for (int k = 0; k < NB1; ++k) {
            float kr = jok ? Kre[j*NB1+k] : 0.f;
            float ki = jok ? Kim[j*NB1+k] : 0.f;
            const float4* crow = (const float4*)(&cmat[k][0]);
            #pragma unroll
            for (int eh = 0; eh < BT / 2; ++eh) {
                float4 c2 = crow[eh];
                ar[2*eh]   = fmaf(kr, c2.x, fmaf(-ki, c2.y, ar[2*eh]));
                ai[2*eh]   = fmaf(kr, c2.y, fmaf( ki, c2.x, ai[2*eh]));
                ar[2*eh+1] = fmaf(kr, c2.z, fmaf(-ki, c2.w, ar[2*eh+1]));
                ai[2*eh+1] = fmaf(kr, c2.w, fmaf( ki, c2.z, ai[2*eh+1]));
            }
        }
        float md = 0.f;
        #pragma unroll
        for (int e = 0; e < BT; ++e) {
            float vmn = sqrtf(ar[e]*ar[e] + ai[e]*ai[e]);
            float vmo = sqrtf(vr[e]*vr[e] + vi[e]*vi[e]);
            md = fmaxf(md, fabsf(vmn - vmo));
            vr[e] = ar[e]; vi[e] = ai[e];
        }
        #pragma unroll
        for (int off = 32; off > 0; off >>= 1) md = fmaxf(md, __shfl_xor(md, off));
        if ((tid & 63) == 0) red[tid >> 6] = md;
        __syncthreads();
        if (fmaxf(red[0], red[1]) < 1e-6f) break;
    }
    #pragma unroll
    for (int e = 0; e < BT; ++e) {
        float vm = sqrtf(vr[e]*vr[e] + vi[e]*vi[e]);
        vls[j][e] = jok ? fminf(0.f, 0.05f - fabsf(1.0f - vm)) : 0.f;
    }
    __syncthreads();
    if (tid < BT) {
        float s = 0.f;
        for (int k = 0; k < NB1; ++k) s += vls[k][tid];
        out[e0 + tid] = 1000.0f * s + costs_s[tid] + usat_s[tid];
    }
}

extern "C" void kernel_launch(void* const* d_in, const int* in_sizes, int n_in,
                              void* d_out, int out_size, void* d_ws, size_t ws_size,
                              hipStream_t stream) {
    const float* action = (const float*)d_in[0];
    const float* state  = (const float*)d_in[1];
    const float* Kre    = (const float*)d_in[2];
    const float* Kim    = (const float*)d_in[3];
    const float* Lre    = (const float*)d_in[4];
    const float* Lim    = (const float*)d_in[5];
    float* out = (float*)d_out;
    const int B = out_size;                        // 32768

    if (ws_size >= (size_t)B * sizeof(float)) {
        float* s2arr = (float*)d_ws;
        hipLaunchKernelGGL(k_fast, dim3(B / 8), dim3(TPB), 0, stream,
                           action, state, s2arr, out);
        hipLaunchKernelGGL(k_post, dim3(PBLK), dim3(TPB), 0, stream,
                           action, state, Kre, Kim, Lre, Lim, s2arr, out, B);
    } else {
        hipLaunchKernelGGL(k_main, dim3((B + BT - 1) / BT), dim3(STPB), 0, stream,
                           action, state, Kre, Kim, Lre, Lim, out);
    }
}

// Round 12
// 37.651 us; speedup vs baseline: 1.5699x; 1.5699x over previous
//
#include <hip/hip_runtime.h>

#define NB1   123
#define NCSd  96
#define SW    538
#define TPB   256
#define BT    16
#define STPB  128

// ---------------- ws layout ----------------
// [0]  u32  count (# flagged elements)           (zeroed by k_norm block 0)
// [1]  f32  dW2 = max_j |W_j - 1|^2              (k_norm block 0)
// [2..18) f32 per-block partial max of ||K_j||^2 (k_norm block i -> slot 2+i)
// [18..18+B) u32 flagged element indices

// ---- R/dW partials: 16 blocks x 4 waves; wave handles rows wid and wid+64 ----
__global__ __launch_bounds__(256) void k_norm(const float* __restrict__ Kre,
                                              const float* __restrict__ Kim,
                                              const float* __restrict__ Lre,
                                              const float* __restrict__ Lim,
                                              float* __restrict__ ws) {
    __shared__ float part[4];
    const int tid = threadIdx.x;
    const int w = tid >> 6, l = tid & 63;
    const int wid = blockIdx.x * 4 + w;              // 0..63
    const int j1 = wid, j2 = wid + 64;
    const bool has2 = j2 < NB1;

    const float* kr1 = Kre + j1 * NB1; const float* ki1 = Kim + j1 * NB1;
    float a0 = kr1[l], b0 = ki1[l];
    float a1 = 0.f, b1 = 0.f;
    if (l < NB1 - 64) { a1 = kr1[l + 64]; b1 = ki1[l + 64]; }
    float c0 = 0.f, d0 = 0.f, c1 = 0.f, d1 = 0.f;
    if (has2) {
        const float* kr2 = Kre + j2 * NB1; const float* ki2 = Kim + j2 * NB1;
        c0 = kr2[l]; d0 = ki2[l];
        if (l < NB1 - 64) { c1 = kr2[l + 64]; d1 = ki2[l + 64]; }
    }
    float s1 = fmaf(a0, a0, b0 * b0) + fmaf(a1, a1, b1 * b1);
    float s2 = fmaf(c0, c0, d0 * d0) + fmaf(c1, c1, d1 * d1);
    #pragma unroll
    for (int off = 32; off; off >>= 1) {
        s1 += __shfl_xor(s1, off);
        s2 += __shfl_xor(s2, off);
    }
    float m2 = has2 ? fmaxf(s1, s2) : s1;
    if (l == 0) part[w] = m2;
    __syncthreads();
    if (tid == 0)
        ws[2 + blockIdx.x] = fmaxf(fmaxf(part[0], part[1]), fmaxf(part[2], part[3]));

    if (blockIdx.x == 0 && w == 0) {
        float dr = Lre[l] - 1.f, di = Lim[l];
        float d2 = fmaf(dr, dr, di * di);
        if (l + 64 < NB1) {
            float dr2 = Lre[l + 64] - 1.f, di2 = Lim[l + 64];
            d2 = fmaxf(d2, fmaf(dr2, dr2, di2 * di2));
        }
        #pragma unroll
        for (int off = 32; off; off >>= 1) d2 = fmaxf(d2, __shfl_xor(d2, off));
        if (l == 0) { ws[1] = d2; ((unsigned*)ws)[0] = 0u; }
    }
}

// ---- main: 2 elements per wave, float4 staging, direct action, in-wave cert ----
// No explicit lgkmcnt drains: DS pipe is in-order per wave; compiler inserts
// counted waits before each dependent use (full drain was a serialization point).
__global__ __launch_bounds__(TPB) void k_fast(const float* __restrict__ action,
                                              const float* __restrict__ state,
                                              float* __restrict__ ws,
                                              float* __restrict__ out) {
    __shared__ __align__(16) float st[4][1088];      // 2 state rows per wave (1076 used)
    __shared__ float ev[4][256];                     // 2 bus histograms per wave

    const int tid = threadIdx.x;
    const int w = tid >> 6, l = tid & 63;
    const long g = (long)blockIdx.x * 4 + w;         // wave id = element pair

    // ---- issue ALL global loads as dwordx4 before any use ----
    const float4* G4 = (const float4*)(state + g * (2 * SW));    // 4304B: 16B aligned
    float4 v0 = G4[l];
    float4 v1 = G4[l + 64];
    float4 v2 = G4[l + 128];
    float4 v3 = G4[l + 192];
    float4 v4 = make_float4(0.f, 0.f, 0.f, 0.f);
    const bool t4 = l < 269 - 256;                   // 13 tail lanes
    if (t4) v4 = G4[l + 256];

    // certificate inputs (L2-hot, issue early)
    float r2p = (l < 16) ? ws[2 + l] : 0.f;
    float dw2 = ws[1];

    // zero ev while loads are in flight (LDS-only)
    ev[w][l] = 0.f; ev[w][l + 64] = 0.f;
    ev[w][l + 128] = 0.f; ev[w][l + 192] = 0.f;

    // ---- LDS stores (hw waits vmcnt per dependence; DS pipe in-order per wave) ----
    float4* st4 = (float4*)st[w];
    st4[l] = v0; st4[l + 64] = v1; st4[l + 128] = v2; st4[l + 192] = v3;
    if (t4) st4[l + 256] = v4;

    // ---- per-element phase: 32 lanes each ----
    const int e = l >> 5, li = l & 31;
    const long b = 2 * g + e;
    const float* srow = st[w] + e * SW;
    const float* actp = action + b * NCSd;           // coalesced per 32-lane group
    float* evp = ev[w] + e * 128;
    const float pr = srow[3];

    float cost = 0.f, usat = 0.f;
    #pragma unroll
    for (int s = 0; s < 3; ++s) {
        int i = li + 32 * s;
        float cap = srow[250 + 3 * i];               // stride-3: conflict-free
        float tl  = srow[251 + 3 * i];
        int   bus = (int)srow[252 + 3 * i];
        float a   = actp[i];
        float conn = cap > 0.f ? 1.f : 0.f;
        float mch = fminf(22.0f,  conn * (70.0f - cap) * 4.0f);   // /DT, DT=0.25
        float mds = fmaxf(-22.0f, conn * (15.0f - cap) * 4.0f);
        float p = fmaxf(fminf(22.17f * a, mch), mds);             // MAX_CS = -MIN_CS
        cost = fmaf(pr * p, 0.25f, cost);
        float nc = ceilf((cap + p * 0.25f) * 100.0f) * 0.01f;
        if (tl == 1.0f) { float d = nc - 70.0f; usat = fmaf(-10.0f * d, d, usat); }
        atomicAdd(&evp[bus], p);
    }

    // s2 = |1000*S|^2 = sum_k (ap+ev)^2 + rp^2  (DS in-order: atomics precede reads)
    float s2 = 0.f;
    #pragma unroll
    for (int s = 0; s < 4; ++s) {
        int k = li + 32 * s;
        if (k < NB1) {
            float apv = srow[4 + k] + evp[k];
            float rpv = srow[127 + k];
            s2 = fmaf(apv, apv, fmaf(rpv, rpv, s2));
        }
    }
    #pragma unroll
    for (int off = 16; off; off >>= 1) {
        s2   += __shfl_xor(s2, off);
        cost += __shfl_xor(cost, off);
        usat += __shfl_xor(usat, off);
    }

    // ---- certificate: closed-form threshold from slots (once per wave) ----
    #pragma unroll
    for (int off = 8; off; off >>= 1) r2p = fmaxf(r2p, __shfl_xor(r2p, off));
    float R  = sqrtf(__shfl(r2p, 0));
    float dW = sqrtf(dw2);
    // safe <=> x < t*(1-dW-t), t = 0.0495-dW  (exact inversion of dW + x/m(x) < 0.0495)
    float t = 0.0495f - dW;
    float q2max = -1.0f;
    if (t > 0.f && t < 1.0f - dW) {
        float xm = (t * (1.0f - dW - t) - 1e-7f) / 1.001f;   // undo fp-safety inflation
        if (xm > 0.f && R > 0.f) {
            float sm = xm / R * 1000.0f;                      // s-scale (S = s/1000)
            q2max = sm * sm;
        }
    }
    bool safe = s2 <= q2max;

    if (li == 0) out[b] = cost + usat;               // voltage term certified zero

    bool flagged = (li == 0) && !safe;
    unsigned long long mask = __ballot(flagged);
    if (mask) {
        int nf = __popcll(mask);
        int lead = __ffsll((long long)mask) - 1;
        unsigned base_ = 0;
        if (l == lead) base_ = atomicAdd((unsigned*)ws, (unsigned)nf);
        base_ = __shfl(base_, lead);
        if (flagged) {
            int rank = __popcll(mask & ((1ull << l) - 1ull));
            ((unsigned*)ws)[18 + base_ + rank] = (unsigned)b;
        }
    }
}

// ---- batched exact solve for flagged elements (expected: none) ----
__global__ __launch_bounds__(STPB) void k_solve(const float* __restrict__ action,
                                                const float* __restrict__ state,
                                                const float* __restrict__ Kre,
                                                const float* __restrict__ Kim,
                                                const float* __restrict__ Lre,
                                                const float* __restrict__ Lim,
                                                const float* __restrict__ ws,
                                                float* __restrict__ out) {
    __shared__ float ev[BT][STPB];
    __shared__ __align__(16) float2 cmat[STPB][BT + 2];
    __shared__ float vls[STPB][BT + 1];
    __shared__ float red[2];
    __shared__ unsigned idxs[BT];
    const unsigned count = ((const unsigned*)ws)[0];
    const int tid = threadIdx.x;
    const int j = tid;
    const bool jok = j < NB1;
    const float Wre = jok ? Lre[j] : 1.f;
    const float Wim = jok ? Lim[j] : 0.f;

    for (unsigned base = (unsigned)blockIdx.x * BT; base < count; base += (unsigned)gridDim.x * BT) {
        unsigned nv = count - base; if (nv > BT) nv = BT;
        if (tid < BT) {
            unsigned t = (unsigned)tid < nv ? (unsigned)tid : nv - 1;
            idxs[tid] = ((const unsigned*)ws)[18 + base + t];
        }
        for (int x = tid; x < BT * STPB; x += STPB) ((float*)ev)[x] = 0.f;
        __syncthreads();

        for (int task = tid; task < BT * NCSd; task += STPB) {
            int e = task / NCSd, i = task - e * NCSd;
            long b = (long)idxs[e];
            const float* srow = state + b * SW;
            float cap = srow[250 + 3 * i];
            int   bus = (int)srow[252 + 3 * i];
            float a   = action[b * NCSd + i];
            float conn = cap > 0.f ? 1.f : 0.f;
            float mch = fminf(22.0f,  conn * (70.0f - cap) * 4.0f);
            float mds = fmaxf(-22.0f, conn * (15.0f - cap) * 4.0f);
            float p = fmaxf(fminf(22.17f * a, mch), mds);
            atomicAdd(&ev[e][bus], p);
        }
        __syncthreads();

        float Sre[BT], Sim[BT], vr[BT], vi[BT];
        #pragma unroll
        for (int e = 0; e < BT; ++e) {
            long b = (long)idxs[e];
            float ap = jok ? state[b * SW + 4 + j]   : 0.f;
            float rp = jok ? state[b * SW + 127 + j] : 0.f;
            Sre[e] = (ap + ev[e][j]) * 0.001f;
            Sim[e] = rp * 0.001f;
            vr[e] = 1.f; vi[e] = 0.f;
        }
        for (int it = 0; it < 100; ++it) {
            #pragma unroll
            for (int e = 0; e < BT; ++e) {
                float d = vr[e] * vr[e] + vi[e] * vi[e];
                float inv = 1.0f / d;
                cmat[j][e] = make_float2((Sre[e] * vr[e] + Sim[e] * vi[e]) * inv,
                                         (Sre[e] * vi[e] - Sim[e] * vr[e]) * inv);
            }
            __syncthreads();
            float ar[BT], ai[BT];
            #pragma unroll
            for (int e = 0; e < BT; ++e) { ar[e] = Wre; ai[e] = Wim; }
            for (int k = 0; k < NB1; ++k) {
                float kr = jok ? Kre[j * NB1 + k] : 0.f;
                float ki = jok ? Kim[j * NB1 + k] : 0.f;
                const float4* crow = (const float4*)(&cmat[k][0]);
                #pragma unroll
                for (int eh = 0; eh < BT / 2; ++eh) {
                    float4 c2 = crow[eh];
                    ar[2*eh]   = fmaf(kr, c2.x, fmaf(-ki, c2.y, ar[2*eh]));
                    ai[2*eh]   = fmaf(kr, c2.y, fmaf( ki, c2.x, ai[2*eh]));
                    ar[2*eh+1] = fmaf(kr, c2.z, fmaf(-ki, c2.w, ar[2*eh+1]));
                    ai[2*eh+1] = fmaf(kr, c2.w, fmaf( ki, c2.z, ai[2*eh+1]));
                }
            }
            float md = 0.f;
            #pragma unroll
            for (int e = 0; e < BT; ++e) {
                float vmn = sqrtf(ar[e]*ar[e] + ai[e]*ai[e]);
                float vmo = sqrtf(vr[e]*vr[e] + vi[e]*vi[e]);
                md = fmaxf(md, fabsf(vmn - vmo));
                vr[e] = ar[e]; vi[e] = ai[e];
            }
            #pragma unroll
            for (int off = 32; off; off >>= 1) md = fmaxf(md, __shfl_xor(md, off));
            if ((tid & 63) == 0) red[tid >> 6] = md;
            __syncthreads();
            if (fmaxf(red[0], red[1]) < 1e-6f) break;
        }
        #pragma unroll
        for (int e = 0; e < BT; ++e) {
            float vm = sqrtf(vr[e]*vr[e] + vi[e]*vi[e]);
            vls[j][e] = jok ? fminf(0.f, 0.05f - fabsf(1.0f - vm)) : 0.f;
        }
        __syncthreads();
        if (tid < (int)nv) {
            float s = 0.f;
            for (int k = 0; k < NB1; ++k) s += vls[k][tid];
            long b = (long)idxs[tid];
            out[b] += 1000.0f * s;
        }
        __syncthreads();
    }
}

// ================= legacy full-solve path (used only if ws too small) =================
__global__ __launch_bounds__(STPB) void k_main(
    const float* __restrict__ action, const float* __restrict__ state,
    const float* __restrict__ Kre, const float* __restrict__ Kim,
    const float* __restrict__ Lre, const float* __restrict__ Lim,
    float* __restrict__ out)
{
    __shared__ float ev[BT][STPB];
    __shared__ float costs_s[BT];
    __shared__ float usat_s[BT];
    __shared__ __align__(16) float2 cmat[STPB][BT + 2];
    __shared__ float vls[STPB][BT + 1];
    __shared__ float red[2];
    const int tid = threadIdx.x;
    const int e0  = blockIdx.x * BT;
    for (int x = tid; x < BT * STPB; x += STPB) ((float*)ev)[x] = 0.f;
    if (tid < BT) { costs_s[tid] = 0.f; usat_s[tid] = 0.f; }
    __syncthreads();
    for (int task = tid; task < BT * NCSd; task += STPB) {
        int e = task / NCSd, i = task - e * NCSd;
        long b = (long)(e0 + e);
        const float* srow = state + b * SW;
        float cap = srow[250 + 3 * i], tleft = srow[251 + 3 * i];
        int bus = (int)srow[252 + 3 * i];
        float a = action[b * NCSd + i];
        float conn = cap > 0.f ? 1.f : 0.f;
        float mch = fminf(22.0f, conn * (70.0f - cap) * 4.0f);
        float mds = fmaxf(-22.0f, conn * (15.0f - cap) * 4.0f);
        float power = fmaxf(fminf(22.17f * a, mch), mds);
        atomicAdd(&costs_s[e], srow[3] * power * 0.25f);
        float nc = ceilf((cap + power * 0.25f) * 100.0f) * 0.01f;
        if (tleft == 1.0f) { float d = nc - 70.0f; atomicAdd(&usat_s[e], -10.0f * d * d); }
        atomicAdd(&ev[e][bus], power);
    }
    __syncthreads();
    const int j = tid;
    const bool jok = j < NB1;
    float Wre = jok ? Lre[j] : 1.0f, Wim = jok ? Lim[j] : 0.0f;
    float Sre[BT], Sim[BT], vr[BT], vi[BT];
    #pragma unroll
    for (int e = 0; e < BT; ++e) {
        long b = (long)(e0 + e);
        float ap = jok ? state[b * SW + 4 + j] : 0.f;
        float rp = jok ? state[b * SW + 127 + j] : 0.f;
        Sre[e] = (ap + ev[e][j]) * 0.001f; Sim[e] = rp * 0.001f;
        vr[e] = 1.f; vi[e] = 0.f;
    }
    for (int it = 0; it < 100; ++it) {
        #pragma unroll
        for (int e = 0; e < BT; ++e) {
            float d = vr[e]*vr[e] + vi[e]*vi[e];
            float inv = 1.0f / d;
            cmat[j][e] = make_float2((Sre[e]*vr[e] + Sim[e]*vi[e]) * inv,
                                     (Sre[e]*vi[e] - Sim[e]*vr[e]) * inv);
        }
        __syncthreads();
        float ar[BT], ai[BT];
        #pragma unroll
        for (int e = 0; e < BT; ++e) { ar[e] = Wre; ai[e] = Wim; }
        for (int k = 0; k < NB1; ++k) {
            float kr = jok ? Kre[j*NB1+k] : 0.f;
            float ki = jok ? Kim[j*NB1+k] : 0.f;
            const float4* crow = (const float4*)(&cmat[k][0]);
            #pragma unroll
            for (int eh = 0; eh < BT / 2; ++eh) {
                float4 c2 = crow[eh];
                ar[2*eh]   = fmaf(kr, c2.x, fmaf(-ki, c2.y, ar[2*eh]));
                ai[2*eh]   = fmaf(kr, c2.y, fmaf( ki, c2.x, ai[2*eh]));
                ar[2*eh+1] = fmaf(kr, c2.z, fmaf(-ki, c2.w, ar[2*eh+1]));
                ai[2*eh+1] = fmaf(kr, c2.w, fmaf( ki, c2.z, ai[2*eh+1]));
            }
        }
        float md = 0.f;
        #pragma unroll
        for (int e = 0; e < BT; ++e) {
            float vmn = sqrtf(ar[e]*ar[e] + ai[e]*ai[e]);
            float vmo = sqrtf(vr[e]*vr[e] + vi[e]*vi[e]);
            md = fmaxf(md, fabsf(vmn - vmo));
            vr[e] = ar[e]; vi[e] = ai[e];
        }
        #pragma unroll
        for (int off = 32; off > 0; off >>= 1) md = fmaxf(md, __shfl_xor(md, off));
        if ((tid & 63) == 0) red[tid >> 6] = md;
        __syncthreads();
        if (fmaxf(red[0], red[1]) < 1e-6f) break;
    }
    #pragma unroll
    for (int e = 0; e < BT; ++e) {
        float vm = sqrtf(vr[e]*vr[e] + vi[e]*vi[e]);
        vls[j][e] = jok ? fminf(0.f, 0.05f - fabsf(1.0f - vm)) : 0.f;
    }
    __syncthreads();
    if (tid < BT) {
        float s = 0.f;
        for (int k = 0; k < NB1; ++k) s += vls[k][tid];
        out[e0 + tid] = 1000.0f * s + costs_s[tid] + usat_s[tid];
    }
}

extern "C" void kernel_launch(void* const* d_in, const int* in_sizes, int n_in,
                              void* d_out, int out_size, void* d_ws, size_t ws_size,
                              hipStream_t stream) {
    const float* action = (const float*)d_in[0];
    const float* state  = (const float*)d_in[1];
    const float* Kre    = (const float*)d_in[2];
    const float* Kim    = (const float*)d_in[3];
    const float* Lre    = (const float*)d_in[4];
    const float* Lim    = (const float*)d_in[5];
    float* out = (float*)d_out;
    const int B = out_size;                        // 32768

    const size_t wsNeed = (size_t)(18 + B) * sizeof(unsigned);
    if (ws_size >= wsNeed) {
        float* ws = (float*)d_ws;
        hipLaunchKernelGGL(k_norm, dim3(16), dim3(256), 0, stream, Kre, Kim, Lre, Lim, ws);
        hipLaunchKernelGGL(k_fast, dim3(B / 8), dim3(TPB), 0, stream,
                           action, state, ws, out);
        hipLaunchKernelGGL(k_solve, dim3(16), dim3(STPB), 0, stream,
                           action, state, Kre, Kim, Lre, Lim, ws, out);
    } else {
        hipLaunchKernelGGL(k_main, dim3((B + BT - 1) / BT), dim3(STPB), 0, stream,
                           action, state, Kre, Kim, Lre, Lim, out);
    }
}